// Round 17
// baseline (1518.265 us; speedup 1.0000x reference)
//
#include <hip/hip_runtime.h>
#include <hip/hip_bf16.h>
#include <stdint.h>
#include <string.h>

constexpr int cB = 32, cS = 128, cT = 64, cH = 512, cH4 = 2048, cVT = 32000, cTM1 = 63;

typedef __attribute__((ext_vector_type(8))) __bf16 bf16x8;
typedef __attribute__((ext_vector_type(4))) float f32x4;

__device__ __forceinline__ float sigm(float x) { return 1.0f / (1.0f + expf(-x)); }

// ---- coherence-point (L3) bypass ops: cross-XCD visible without fences ----
__device__ __forceinline__ bf16x8 sc_load16(const __hip_bfloat16* p) {
  bf16x8 r;
  asm volatile("global_load_dwordx4 %0, %1, off sc0 sc1"
               : "=&v"(r) : "v"(p) : "memory");
  return r;
}
__device__ __forceinline__ unsigned sc_load4u(const __hip_bfloat16* p) {
  unsigned r;
  asm volatile("global_load_dword %0, %1, off sc0 sc1"
               : "=&v"(r) : "v"(p) : "memory");
  return r;
}
__device__ __forceinline__ void sc_store4(__hip_bfloat16* p, unsigned v) {
  asm volatile("global_store_dword %0, %1, off sc0 sc1"
               :: "v"(p), "v"(v) : "memory");
}
__device__ __forceinline__ void pl_store4(__hip_bfloat16* p, unsigned v) {
  asm volatile("global_store_dword %0, %1, off"
               :: "v"(p), "v"(v) : "memory");
}
__device__ __forceinline__ unsigned sc_loadu(const unsigned* p) {
  unsigned r;
  asm volatile("global_load_dword %0, %1, off sc0 sc1"
               : "=&v"(r) : "v"(p) : "memory");
  asm volatile("s_waitcnt vmcnt(0)" ::: "memory");
  return r;
}
__device__ __forceinline__ void sc_storeu(unsigned* p, unsigned v) {
  asm volatile("global_store_dword %0, %1, off sc0 sc1"
               :: "v"(p), "v"(v) : "memory");
}

// ---------------- f2bT tile helper (256 threads): fp32 [K][N] tile -> bf16 [N][K] ----------------
__device__ __forceinline__ void f2bT_tile(const float* __restrict__ src,
                                          __hip_bfloat16* __restrict__ dst,
                                          int K, int N, int gi, int bx, int by,
                                          float (*t)[33]) {
  int nt = bx * 32, kt = by * 32;
  int c = threadIdx.x & 31, r0 = threadIdx.x >> 5;
#pragma unroll
  for (int i = 0; i < 4; ++i) {
    int r = r0 + i * 8;
    t[r][c] = src[(size_t)(kt + r) * N + nt + c];
  }
  __syncthreads();
#pragma unroll
  for (int i = 0; i < 4; ++i) {
    int row = nt + r0 + i * 8;
    int pr = gi ? (((row & 511) << 2) | (row >> 9)) : row;
    dst[(size_t)pr * K + kt + c] = __float2bfloat16(t[c][r0 + i * 8]);
  }
  __syncthreads();
}

// 512-thread variant (decoder side blocks)
__device__ __forceinline__ void f2bT_tile512(const float* __restrict__ src,
                                             __hip_bfloat16* __restrict__ dst,
                                             int K, int N, int bx, int by,
                                             float (*t)[33]) {
  int nt = bx * 32, kt = by * 32;
  int c = threadIdx.x & 31, r0 = (threadIdx.x >> 5) & 15;
#pragma unroll
  for (int i = 0; i < 2; ++i) {
    int r = r0 + i * 16;
    t[r][c] = src[(size_t)(kt + r) * N + nt + c];
  }
  __syncthreads();
#pragma unroll
  for (int i = 0; i < 2; ++i) {
    int row = nt + r0 + i * 16;
    dst[(size_t)row * K + kt + c] = __float2bfloat16(t[c][r0 + i * 16]);
  }
  __syncthreads();
}

// ---------------- mega-prep: weights + biases + embeds + pads + barrier init ----------------
__global__ __launch_bounds__(256) void k_prep(
    const float* __restrict__ Wf, const float* __restrict__ Wb, const float* __restrict__ Wd,
    const float* __restrict__ Uf, const float* __restrict__ Ub, const float* __restrict__ Ud,
    const float* __restrict__ fcW,
    const float* __restrict__ bf, const float* __restrict__ bb, const float* __restrict__ bd,
    const int* __restrict__ src, const int* __restrict__ trg,
    const float* __restrict__ E_src, const float* __restrict__ E_trg,
    __hip_bfloat16* __restrict__ Wtfx, __hip_bfloat16* __restrict__ Wtbx,
    __hip_bfloat16* __restrict__ Wtdx,
    __hip_bfloat16* __restrict__ Utf, __hip_bfloat16* __restrict__ Utb,
    __hip_bfloat16* __restrict__ Utd,
    __hip_bfloat16* __restrict__ fcWt,
    float* __restrict__ bfx, float* __restrict__ bbx, float* __restrict__ bdx,
    __hip_bfloat16* __restrict__ xs_bf, __hip_bfloat16* __restrict__ ys_bf,
    float* __restrict__ neg, __hip_bfloat16* __restrict__ catb,
    unsigned* __restrict__ bars) {
  __shared__ float t[32][33];
  int id = blockIdx.x;
  int tid = threadIdx.x;
  if (id < 6144) {
    int grp = id >> 10, r = id & 1023;
    const float* s; __hip_bfloat16* d;
    switch (grp) {
      case 0: s = Wf; d = Wtfx; break;
      case 1: s = Wb; d = Wtbx; break;
      case 2: s = Wd; d = Wtdx; break;
      case 3: s = Uf; d = Utf; break;
      case 4: s = Ub; d = Utb; break;
      default: s = Ud; d = Utd; break;
    }
    f2bT_tile(s, d, 512, 2048, 1, r & 63, r >> 6, t);
  } else if (id < 6656) {
    int r = id - 6144;
    f2bT_tile(fcW, fcWt, 1024, 512, 0, r & 15, r >> 4, t);
  } else if (id < 6680) {
    int r = id - 6656;
    const float* s = (r < 8) ? bf : ((r < 16) ? bb : bd);
    float* d = (r < 8) ? bfx : ((r < 16) ? bbx : bdx);
    int i = (r & 7) * 256 + tid;
    d[i] = s[(i & 3) * 512 + (i >> 2)];
  } else if (id < 6744) {
    int r = id - 6680;                        // ys zero-pad rows 2016..2047
    ys_bf[(size_t)2016 * 512 + r * 256 + tid] = __float2bfloat16(0.0f);
  } else if (id < 6776) {
    int r = id - 6744;                        // cat zero rows 4160..4223
    __hip_bfloat16* d = catb + (size_t)4160 * 1024 + (size_t)r * 2048 + tid * 8;
    bf16x8 zv = {};
    *(bf16x8*)d = zv;
  } else if (id < 8824) {
    int r = id - 6776;                        // src embed: rows 2r, 2r+1
    int half = tid >> 7, sb = 2 * r + half;
    int s = sb >> 5, b = sb & 31;
    int tok = src[b * cS + s];
    int cg = tid & 127;
    float4 e = ((const float4*)(E_src + (size_t)tok * cH))[cg];
    __hip_bfloat16* drow = xs_bf + (size_t)sb * cH + cg * 4;
    drow[0] = __float2bfloat16(e.x); drow[1] = __float2bfloat16(e.y);
    drow[2] = __float2bfloat16(e.z); drow[3] = __float2bfloat16(e.w);
    if (cg == 0) neg[b * cS + s] = (tok == 0) ? -1e9f : 0.0f;
  } else if (id < 9832) {
    int r = id - 8824;                        // trg embed: rows 2r, 2r+1
    int half = tid >> 7, tb = 2 * r + half;
    int tt = tb >> 5, b = tb & 31;
    int tok = trg[b * cT + tt];
    int cg = tid & 127;
    float4 e = ((const float4*)(E_trg + (size_t)tok * cH))[cg];
    __hip_bfloat16* drow = ys_bf + (size_t)tb * cH + cg * 4;
    drow[0] = __float2bfloat16(e.x); drow[1] = __float2bfloat16(e.y);
    drow[2] = __float2bfloat16(e.z); drow[3] = __float2bfloat16(e.w);
  } else {
    if (tid < 64) bars[tid] = 0u;             // barrier slots
  }
}

// ---------------- bf16 MFMA GEMM: C[M,N] = A[M,K] @ Bt[N,K]^T + bias ----------------
__global__ __launch_bounds__(256) void k_bgemm(const __hip_bfloat16* __restrict__ A,
                                               const __hip_bfloat16* __restrict__ Bt,
                                               const float* __restrict__ bias,
                                               float* __restrict__ C,
                                               int M, int K, int N) {
  __shared__ __hip_bfloat16 As[128 * 64];
  __shared__ __hip_bfloat16 Bs[128 * 64];
  const int tid = threadIdx.x;
  const int lane = tid & 63;
  const int wave = tid >> 6;
  const int wr = wave >> 1, wc = wave & 1;
  const int bm = blockIdx.x * 128, bn = blockIdx.y * 128;

  f32x4 acc[4][4] = {};

  const int srow = lane >> 3;
  const int scol = (lane & 7) * 8;

  for (int kt = 0; kt < K; kt += 64) {
#pragma unroll
    for (int i = 0; i < 4; ++i) {
      int c = wave * 4 + i;
      const __hip_bfloat16* ga = A + (size_t)(bm + c * 8 + srow) * K + kt + scol;
      __builtin_amdgcn_global_load_lds(
          (const __attribute__((address_space(1))) uint32_t*)ga,
          (__attribute__((address_space(3))) uint32_t*)(As + c * 512), 16, 0, 0);
      const __hip_bfloat16* gb = Bt + (size_t)(bn + c * 8 + srow) * K + kt + scol;
      __builtin_amdgcn_global_load_lds(
          (const __attribute__((address_space(1))) uint32_t*)gb,
          (__attribute__((address_space(3))) uint32_t*)(Bs + c * 512), 16, 0, 0);
    }
    __syncthreads();

#pragma unroll
    for (int kk = 0; kk < 64; kk += 32) {
      const int ko = kk + (lane >> 4) * 8;
      bf16x8 a[4], b[4];
      const int ar = wr * 64 + (lane & 15);
#pragma unroll
      for (int m = 0; m < 4; ++m)
        a[m] = *(const bf16x8*)(As + (size_t)(ar + m * 16) * 64 + ko);
      const int br = wc * 64 + (lane & 15);
#pragma unroll
      for (int n = 0; n < 4; ++n)
        b[n] = *(const bf16x8*)(Bs + (size_t)(br + n * 16) * 64 + ko);
#pragma unroll
      for (int m = 0; m < 4; ++m)
#pragma unroll
        for (int n = 0; n < 4; ++n)
          acc[m][n] = __builtin_amdgcn_mfma_f32_16x16x32_bf16(a[m], b[n], acc[m][n], 0, 0, 0);
    }
    __syncthreads();
  }

#pragma unroll
  for (int m = 0; m < 4; ++m) {
    const int row0 = bm + wr * 64 + m * 16 + (lane >> 4) * 4;
#pragma unroll
    for (int n = 0; n < 4; ++n) {
      const int col = bn + wc * 64 + n * 16 + (lane & 15);
      const float bv = bias[col];
#pragma unroll
      for (int r = 0; r < 4; ++r) {
        const int row = row0 + r;
        if (row < M) C[(size_t)row * N + col] = acc[m][n][r] + bv;
      }
    }
  }
}

// ws-half classifier pass2: A=decb cols 0..512 (stride 1024), Bt=clsWt cols 0..512
// (stride 1024), C = out += acc + bias, rows remapped r=t*32+b -> b*63+t
__global__ __launch_bounds__(256) void k_bgemm_ws(const __hip_bfloat16* __restrict__ A,
                                                  const __hip_bfloat16* __restrict__ Bt,
                                                  const float* __restrict__ bias,
                                                  float* __restrict__ C) {
  __shared__ __hip_bfloat16 As[128 * 64];
  __shared__ __hip_bfloat16 Bs[128 * 64];
  const int tid = threadIdx.x;
  const int lane = tid & 63;
  const int wave = tid >> 6;
  const int wr = wave >> 1, wc = wave & 1;
  const int bm = blockIdx.x * 128, bn = blockIdx.y * 128;

  f32x4 acc[4][4] = {};
  const int srow = lane >> 3;
  const int scol = (lane & 7) * 8;

  for (int kt = 0; kt < 512; kt += 64) {
#pragma unroll
    for (int i = 0; i < 4; ++i) {
      int c = wave * 4 + i;
      const __hip_bfloat16* ga = A + (size_t)(bm + c * 8 + srow) * 1024 + kt + scol;
      __builtin_amdgcn_global_load_lds(
          (const __attribute__((address_space(1))) uint32_t*)ga,
          (__attribute__((address_space(3))) uint32_t*)(As + c * 512), 16, 0, 0);
      const __hip_bfloat16* gb = Bt + (size_t)(bn + c * 8 + srow) * 1024 + kt + scol;
      __builtin_amdgcn_global_load_lds(
          (const __attribute__((address_space(1))) uint32_t*)gb,
          (__attribute__((address_space(3))) uint32_t*)(Bs + c * 512), 16, 0, 0);
    }
    __syncthreads();
#pragma unroll
    for (int kk = 0; kk < 64; kk += 32) {
      const int ko = kk + (lane >> 4) * 8;
      bf16x8 a[4], b[4];
      const int ar = wr * 64 + (lane & 15);
#pragma unroll
      for (int m = 0; m < 4; ++m)
        a[m] = *(const bf16x8*)(As + (size_t)(ar + m * 16) * 64 + ko);
      const int br = wc * 64 + (lane & 15);
#pragma unroll
      for (int n = 0; n < 4; ++n)
        b[n] = *(const bf16x8*)(Bs + (size_t)(br + n * 16) * 64 + ko);
#pragma unroll
      for (int m = 0; m < 4; ++m)
#pragma unroll
        for (int n = 0; n < 4; ++n)
          acc[m][n] = __builtin_amdgcn_mfma_f32_16x16x32_bf16(a[m], b[n], acc[m][n], 0, 0, 0);
    }
    __syncthreads();
  }

#pragma unroll
  for (int m = 0; m < 4; ++m) {
    const int row0 = bm + wr * 64 + m * 16 + (lane >> 4) * 4;
#pragma unroll
    for (int n = 0; n < 4; ++n) {
      const int col = bn + wc * 64 + n * 16 + (lane & 15);
      const float bv = bias[col];
#pragma unroll
      for (int r = 0; r < 4; ++r) {
        const int row = row0 + r;
        if (row < 2016) {
          int orow = (row & 31) * 63 + (row >> 5);
          float* cp = C + (size_t)orow * 32000 + col;
          *cp = acc[m][n][r] + bv + *cp;
        }
      }
    }
  }
}

// z-merged variant for the two encoder input projections
__global__ __launch_bounds__(256) void k_bgemm2(
    const __hip_bfloat16* __restrict__ A,
    const __hip_bfloat16* __restrict__ Bt0, const __hip_bfloat16* __restrict__ Bt1,
    const float* __restrict__ bias0, const float* __restrict__ bias1,
    float* __restrict__ C0, float* __restrict__ C1,
    int M, int K, int N) {
  const __hip_bfloat16* Bt = blockIdx.z ? Bt1 : Bt0;
  const float* bias = blockIdx.z ? bias1 : bias0;
  float* C = blockIdx.z ? C1 : C0;

  __shared__ __hip_bfloat16 As[128 * 64];
  __shared__ __hip_bfloat16 Bs[128 * 64];
  const int tid = threadIdx.x;
  const int lane = tid & 63;
  const int wave = tid >> 6;
  const int wr = wave >> 1, wc = wave & 1;
  const int bm = blockIdx.x * 128, bn = blockIdx.y * 128;

  f32x4 acc[4][4] = {};
  const int srow = lane >> 3;
  const int scol = (lane & 7) * 8;

  for (int kt = 0; kt < K; kt += 64) {
#pragma unroll
    for (int i = 0; i < 4; ++i) {
      int c = wave * 4 + i;
      const __hip_bfloat16* ga = A + (size_t)(bm + c * 8 + srow) * K + kt + scol;
      __builtin_amdgcn_global_load_lds(
          (const __attribute__((address_space(1))) uint32_t*)ga,
          (__attribute__((address_space(3))) uint32_t*)(As + c * 512), 16, 0, 0);
      const __hip_bfloat16* gb = Bt + (size_t)(bn + c * 8 + srow) * K + kt + scol;
      __builtin_amdgcn_global_load_lds(
          (const __attribute__((address_space(1))) uint32_t*)gb,
          (__attribute__((address_space(3))) uint32_t*)(Bs + c * 512), 16, 0, 0);
    }
    __syncthreads();
#pragma unroll
    for (int kk = 0; kk < 64; kk += 32) {
      const int ko = kk + (lane >> 4) * 8;
      bf16x8 a[4], b[4];
      const int ar = wr * 64 + (lane & 15);
#pragma unroll
      for (int m = 0; m < 4; ++m)
        a[m] = *(const bf16x8*)(As + (size_t)(ar + m * 16) * 64 + ko);
      const int br = wc * 64 + (lane & 15);
#pragma unroll
      for (int n = 0; n < 4; ++n)
        b[n] = *(const bf16x8*)(Bs + (size_t)(br + n * 16) * 64 + ko);
#pragma unroll
      for (int m = 0; m < 4; ++m)
#pragma unroll
        for (int n = 0; n < 4; ++n)
          acc[m][n] = __builtin_amdgcn_mfma_f32_16x16x32_bf16(a[m], b[n], acc[m][n], 0, 0, 0);
    }
    __syncthreads();
  }
#pragma unroll
  for (int m = 0; m < 4; ++m) {
    const int row0 = bm + wr * 64 + m * 16 + (lane >> 4) * 4;
#pragma unroll
    for (int n = 0; n < 4; ++n) {
      const int col = bn + wc * 64 + n * 16 + (lane & 15);
      const float bv = bias[col];
#pragma unroll
      for (int r = 0; r < 4; ++r) {
        const int row = row0 + r;
        if (row < M) C[(size_t)row * N + col] = acc[m][n][r] + bv;
      }
    }
  }
}

// ---- slot-array grid barrier (16 blocks): fire-and-forget arrive + wave0 ballot poll ----
#define SLOT_BARRIER(SLOTS, NB, GEN)                                             \
  {                                                                              \
    asm volatile("s_waitcnt vmcnt(2)" ::: "memory");                             \
    __builtin_amdgcn_sched_barrier(0);                                           \
    __builtin_amdgcn_s_barrier();                                                \
    if (tid == 0) sc_storeu((SLOTS) + (NB), (unsigned)(GEN));                    \
    if (wv == 0) {                                                               \
      for (;;) {                                                                 \
        unsigned v = sc_loadu((SLOTS) + (lane & 15));                            \
        if (__all((lane >= 16) | (v >= (unsigned)(GEN)))) break;                 \
        __builtin_amdgcn_s_sleep(1);                                             \
      }                                                                          \
    }                                                                            \
    __builtin_amdgcn_s_barrier();                                                \
    __builtin_amdgcn_sched_barrier(0);                                           \
  }

// ================= persistent MFMA encoder: blocks 0-31 recurrence (16/dir, 512 thr),
// blocks 32-255: yW projection =================
#define ENC_STEP(T, ZI0, ZI1, ZO0, ZO1)                                          \
  {                                                                              \
    const int t = (T);                                                           \
    const int trow = dir ? (127 - t) : t;                                        \
    if (t > 0) {                                                                 \
      const __hip_bfloat16* hsrc = hcur + (size_t)((t + 1) & 1) * 16384;         \
      bf16x8 hr[4];                                                              \
      _Pragma("unroll")                                                          \
      for (int i = 0; i < 4; ++i) {                                              \
        int c = tid + i * 512;                                                   \
        hr[i] = sc_load16(hsrc + (size_t)c * 8);                                 \
      }                                                                          \
      asm volatile("s_waitcnt vmcnt(0)" ::: "memory");                           \
      __builtin_amdgcn_sched_barrier(0);                                         \
      _Pragma("unroll")                                                          \
      for (int i = 0; i < 4; ++i) {                                              \
        int c = tid + i * 512;                                                   \
        int r = c >> 6, cc = (c & 63) * 8;                                       \
        *(bf16x8*)&Hs[r][cc] = hr[i];                                            \
      }                                                                          \
      asm volatile("s_waitcnt lgkmcnt(0)" ::: "memory");                         \
      __builtin_amdgcn_s_barrier();                                              \
      __builtin_amdgcn_sched_barrier(0);                                         \
    }                                                                            \
    f32x4 acc0 = {}, acc1 = {};                                                  \
    if (t > 0) {                                                                 \
      _Pragma("unroll")                                                          \
      for (int kk = 0; kk < 16; ++kk) {                                          \
        bf16x8 h0v = *(const bf16x8*)&Hs[b0][kk * 32 + fq * 8];                  \
        bf16x8 h1v = *(const bf16x8*)&Hs[b1][kk * 32 + fq * 8];                  \
        acc0 = __builtin_amdgcn_mfma_f32_16x16x32_bf16(afrag[kk], h0v, acc0, 0, 0, 0); \
        acc1 = __builtin_amdgcn_mfma_f32_16x16x32_bf16(afrag[kk], h1v, acc1, 0, 0, 0); \
      }                                                                          \
    }                                                                            \
    {                                                                            \
      float zi = ZI0[0] + acc0[0], zf = ZI0[1] + acc0[1],                        \
            zg = ZI0[2] + acc0[2], zo = ZI0[3] + acc0[3];                        \
      cs0 = sigm(zf) * cs0 + sigm(zi) * tanhf(zg);                               \
      Ho[b0][jloc] = __float2bfloat16(sigm(zo) * tanhf(cs0));                    \
    }                                                                            \
    {                                                                            \
      float zi = ZI1[0] + acc1[0], zf = ZI1[1] + acc1[1],                        \
            zg = ZI1[2] + acc1[2], zo = ZI1[3] + acc1[3];                        \
      cs1 = sigm(zf) * cs1 + sigm(zi) * tanhf(zg);                               \
      Ho[b1][jloc] = __float2bfloat16(sigm(zo) * tanhf(cs1));                    \
    }                                                                            \
    asm volatile("s_waitcnt lgkmcnt(0)" ::: "memory");                           \
    __builtin_amdgcn_s_barrier();                                                \
    __builtin_amdgcn_sched_barrier(0);                                           \
    {                                                                            \
      unsigned v = *(const unsigned*)&Ho[bb][jp];                                \
      sc_store4(hcur + (size_t)(t & 1) * 16384 + (size_t)bb * 512 + nb * 32 + jp, v); \
      pl_store4(catb + ((size_t)(bb * 128 + trow)) * 1024 + dhalf + nb * 32 + jp, v); \
    }                                                                            \
    __builtin_amdgcn_sched_barrier(0);                                           \
    const int tn = (t < 127) ? t + 1 : 127;                                      \
    const int ntrow = dir ? (127 - tn) : tn;                                     \
    ZO0 = *(const f32x4*)(xW + ((size_t)(ntrow * 32 + b0)) * 2048 + zc);         \
    ZO1 = *(const f32x4*)(xW + ((size_t)(ntrow * 32 + b1)) * 2048 + zc);         \
    if (t < 127) SLOT_BARRIER(slots, nb, t + 1);                                 \
  }

__global__ __launch_bounds__(512, 1) void k_enc_mfma(
    const float* __restrict__ xWf, const float* __restrict__ xWb,
    const __hip_bfloat16* __restrict__ Utf, const __hip_bfloat16* __restrict__ Utb,
    __hip_bfloat16* __restrict__ catb,
    __hip_bfloat16* __restrict__ henc,
    unsigned* bars,
    const __hip_bfloat16* __restrict__ ys_bf, const __hip_bfloat16* __restrict__ Wtdx,
    const float* __restrict__ bdx, float* __restrict__ yW) {
  __shared__ __hip_bfloat16 Hs[32][520];
  __shared__ __hip_bfloat16 Ho[32][36];
  __shared__ __hip_bfloat16 As[8192];
  __shared__ __hip_bfloat16 Bs[8192];

  const int tid = threadIdx.x;
  const int lane = tid & 63;
  const int wv = tid >> 6;                  // 0..7

  if (blockIdx.x >= 32) {
    // ---- yW projection: [2048 x 512] @ Wtdx^T -> [2048 x 2048], 256 tiles / 224 blocks ----
    const int sidx = blockIdx.x - 32;
    const int wr = wv >> 2, wc = wv & 3;
    const int fr = lane & 15, fq = lane >> 4;
    for (int tile = sidx; tile < 256; tile += 224) {
      int bm = (tile & 15) * 128, bn = (tile >> 4) * 128;
      f32x4 acc[4][2] = {};
      for (int kt = 0; kt < 512; kt += 64) {
#pragma unroll
        for (int i = 0; i < 2; ++i) {
          int ch = wv * 2 + i;
          const __hip_bfloat16* ga = ys_bf + (size_t)(bm + ch * 8 + (lane >> 3)) * 512 + kt + (lane & 7) * 8;
          __builtin_amdgcn_global_load_lds(
              (const __attribute__((address_space(1))) uint32_t*)ga,
              (__attribute__((address_space(3))) uint32_t*)(As + ch * 512), 16, 0, 0);
          const __hip_bfloat16* gb = Wtdx + (size_t)(bn + ch * 8 + (lane >> 3)) * 512 + kt + (lane & 7) * 8;
          __builtin_amdgcn_global_load_lds(
              (const __attribute__((address_space(1))) uint32_t*)gb,
              (__attribute__((address_space(3))) uint32_t*)(Bs + ch * 512), 16, 0, 0);
        }
        __syncthreads();
#pragma unroll
        for (int kk = 0; kk < 64; kk += 32) {
          const int ko = kk + fq * 8;
          bf16x8 a[4], b[2];
#pragma unroll
          for (int m = 0; m < 4; ++m)
            a[m] = *(const bf16x8*)(As + (size_t)(wr * 64 + m * 16 + fr) * 64 + ko);
#pragma unroll
          for (int n = 0; n < 2; ++n)
            b[n] = *(const bf16x8*)(Bs + (size_t)(wc * 32 + n * 16 + fr) * 64 + ko);
#pragma unroll
          for (int m = 0; m < 4; ++m)
#pragma unroll
            for (int n = 0; n < 2; ++n)
              acc[m][n] = __builtin_amdgcn_mfma_f32_16x16x32_bf16(a[m], b[n], acc[m][n], 0, 0, 0);
        }
        __syncthreads();
      }
#pragma unroll
      for (int m = 0; m < 4; ++m) {
        const int row0 = bm + wr * 64 + m * 16 + fq * 4;
#pragma unroll
        for (int n = 0; n < 2; ++n) {
          const int col = bn + wc * 32 + n * 16 + fr;
          const float bv = bdx[col];
#pragma unroll
          for (int r = 0; r < 4; ++r)
            yW[(size_t)(row0 + r) * 2048 + col] = acc[m][n][r] + bv;
        }
      }
    }
    return;
  }

  const int bid = blockIdx.x;
  const int dir = bid >> 4, nb = bid & 15;
  const int c0 = nb * 128;
  const float* xW = dir ? xWb : xWf;
  const __hip_bfloat16* Ut = dir ? Utb : Utf;
  const int dhalf = dir * 512;
  __hip_bfloat16* hcur = henc + (size_t)dir * 32768;   // [2][32][512] bf16
  unsigned* slots = bars + dir * 16;

  const int fr = lane & 15;
  const int fq = lane >> 4;

  bf16x8 afrag[16];
#pragma unroll
  for (int kk = 0; kk < 16; ++kk)
    afrag[kk] = *(const bf16x8*)(Ut + (size_t)(c0 + wv * 16 + fr) * 512 + kk * 32 + fq * 8);

  const int jloc = wv * 4 + fq;             // 0..31
  const int b0 = fr, b1 = fr + 16;
  const int zc = c0 + wv * 16 + fq * 4;
  const int bb = tid >> 4, jp = (tid & 15) * 2;   // coalesced 64B-row store mapping
  float cs0 = 0.f, cs1 = 0.f;

  const int trow0 = dir ? 127 : 0;
  f32x4 zA0 = *(const f32x4*)(xW + ((size_t)(trow0 * 32 + b0)) * 2048 + zc);
  f32x4 zA1 = *(const f32x4*)(xW + ((size_t)(trow0 * 32 + b1)) * 2048 + zc);
  f32x4 zB0, zB1;

  for (int it = 0; it < 64; ++it) {
    ENC_STEP(2 * it, zA0, zA1, zB0, zB1);
    ENC_STEP(2 * it + 1, zB0, zB1, zA0, zA1);
  }

  // ---- epilogue: final h row (4096+b) + c row (4128+b) straight into cat ----
  {
    unsigned v = *(const unsigned*)&Ho[bb][jp];   // Ho still holds t=127 h
    pl_store4(catb + (size_t)(4096 + bb) * 1024 + dhalf + nb * 32 + jp, v);
  }
  __syncthreads();
  Ho[b0][jloc] = __float2bfloat16(cs0);
  Ho[b1][jloc] = __float2bfloat16(cs1);
  asm volatile("s_waitcnt lgkmcnt(0)" ::: "memory");
  __builtin_amdgcn_s_barrier();
  {
    unsigned v = *(const unsigned*)&Ho[bb][jp];
    pl_store4(catb + (size_t)(4128 + bb) * 1024 + dhalf + nb * 32 + jp, v);
  }
}

// ---------------- 512-thread attention for one (b,t); decb t-major ----------------
__device__ void attn_one(const float* __restrict__ src_h, const float* __restrict__ neg,
                         __hip_bfloat16* __restrict__ decb, int b, int t,
                         float* hv, float* sc, float* red) {
  const int tx = threadIdx.x;
  __hip_bfloat16* drow = decb + ((size_t)(t * 32 + b)) * 1024;
  if (tx < 256) {
    unsigned u = sc_load4u(drow + 512 + tx * 2);
    asm volatile("s_waitcnt vmcnt(0)" ::: "memory");
    hv[tx * 2] = __uint_as_float(u << 16);
    hv[tx * 2 + 1] = __uint_as_float(u & 0xffff0000u);
  }
  __syncthreads();
  {
    int s = tx >> 2, q = tx & 3;
    const float4* sr = (const float4*)(src_h + ((size_t)b * cS + s) * cH + q * 128);
    const float4* hh = (const float4*)(hv + q * 128);
    float acc = 0.f;
#pragma unroll 8
    for (int k = 0; k < 32; ++k) {
      float4 v = sr[k], h4 = hh[k];
      acc += v.x * h4.x + v.y * h4.y + v.z * h4.z + v.w * h4.w;
    }
    acc += __shfl_xor(acc, 1);
    acc += __shfl_xor(acc, 2);
    if (q == 0) {
      float s0 = acc + neg[b * cS + s];
      sc[s] = s0;
      red[s] = s0;
    }
  }
  __syncthreads();
  for (int off = 64; off >= 1; off >>= 1) {
    if (tx < off) red[tx] = fmaxf(red[tx], red[tx + off]);
    __syncthreads();
  }
  float mx = red[0];
  __syncthreads();
  float e = 0.f;
  if (tx < cS) { e = expf(sc[tx] - mx); red[tx] = e; }
  __syncthreads();
  for (int off = 64; off >= 1; off >>= 1) {
    if (tx < off) red[tx] += red[tx + off];
    __syncthreads();
  }
  float inv = 1.0f / red[0];
  __syncthreads();
  if (tx < cS) sc[tx] = e * inv;
  __syncthreads();
  {
    float a = 0.f;
    const float* sr = src_h + (size_t)b * cS * cH + tx;
    for (int s = 0; s < cS; ++s) a += sc[s] * sr[(size_t)s * cH];
    drow[tx] = __float2bfloat16(a);
  }
}

// ================= persistent MFMA decoder: blocks 0-15 recurrence,
// blocks 16-111 attention, blocks 112-255 clsW convert + h-half classifier =================
#define DEC_STEP(T, ZI0, ZI1, ZO0, ZO1)                                          \
  {                                                                              \
    const int t = (T);                                                           \
    if (t == 0) {                                                                \
      const float4* ph4 = (const float4*)prev_h;                                 \
      _Pragma("unroll")                                                          \
      for (int i = 0; i < 8; ++i) {                                              \
        int c = tid + i * 512;                                                   \
        float4 v = ph4[c];                                                       \
        int r = c >> 7, c4 = (c & 127) * 4;                                      \
        Hs[r][c4 + 0] = __float2bfloat16(v.x);                                   \
        Hs[r][c4 + 1] = __float2bfloat16(v.y);                                   \
        Hs[r][c4 + 2] = __float2bfloat16(v.z);                                   \
        Hs[r][c4 + 3] = __float2bfloat16(v.w);                                   \
      }                                                                          \
    } else {                                                                     \
      const __hip_bfloat16* hsrc = hdec + (size_t)((t + 1) & 1) * 16384;         \
      bf16x8 hr[4];                                                              \
      _Pragma("unroll")                                                          \
      for (int i = 0; i < 4; ++i) {                                              \
        int c = tid + i * 512;                                                   \
        hr[i] = sc_load16(hsrc + (size_t)c * 8);                                 \
      }                                                                          \
      asm volatile("s_waitcnt vmcnt(0)" ::: "memory");                           \
      __builtin_amdgcn_sched_barrier(0);                                         \
      _Pragma("unroll")                                                          \
      for (int i = 0; i < 4; ++i) {                                              \
        int c = tid + i * 512;                                                   \
        int r = c >> 6, cc = (c & 63) * 8;                                       \
        *(bf16x8*)&Hs[r][cc] = hr[i];                                            \
      }                                                                          \
    }                                                                            \
    asm volatile("s_waitcnt lgkmcnt(0)" ::: "memory");                           \
    __builtin_amdgcn_s_barrier();                                                \
    __builtin_amdgcn_sched_barrier(0);                                           \
    f32x4 acc0 = {}, acc1 = {};                                                  \
    _Pragma("unroll")                                                            \
    for (int kk = 0; kk < 16; ++kk) {                                            \
      bf16x8 h0v = *(const bf16x8*)&Hs[b0][kk * 32 + fq * 8];                    \
      bf16x8 h1v = *(const bf16x8*)&Hs[b1][kk * 32 + fq * 8];                    \
      acc0 = __builtin_amdgcn_mfma_f32_16x16x32_bf16(afrag[kk], h0v, acc0, 0, 0, 0); \
      acc1 = __builtin_amdgcn_mfma_f32_16x16x32_bf16(afrag[kk], h1v, acc1, 0, 0, 0); \
    }                                                                            \
    {                                                                            \
      float zi = ZI0[0] + acc0[0], zf = ZI0[1] + acc0[1],                        \
            zg = ZI0[2] + acc0[2], zo = ZI0[3] + acc0[3];                        \
      cs0 = sigm(zf) * cs0 + sigm(zi) * tanhf(zg);                               \
      Ho[b0][jloc] = __float2bfloat16(sigm(zo) * tanhf(cs0));                    \
    }                                                                            \
    {                                                                            \
      float zi = ZI1[0] + acc1[0], zf = ZI1[1] + acc1[1],                        \
            zg = ZI1[2] + acc1[2], zo = ZI1[3] + acc1[3];                        \
      cs1 = sigm(zf) * cs1 + sigm(zi) * tanhf(zg);                               \
      Ho[b1][jloc] = __float2bfloat16(sigm(zo) * tanhf(cs1));                    \
    }                                                                            \
    asm volatile("s_waitcnt lgkmcnt(0)" ::: "memory");                           \
    __builtin_amdgcn_s_barrier();                                                \
    __builtin_amdgcn_sched_barrier(0);                                           \
    {                                                                            \
      unsigned v = *(const unsigned*)&Ho[bb][jp];                                \
      sc_store4(hdec + (size_t)(t & 1) * 16384 + (size_t)bb * 512 + nb * 32 + jp, v); \
      sc_store4(decb + ((size_t)(t * 32 + bb)) * 1024 + 512 + nb * 32 + jp, v);  \
    }                                                                            \
    __builtin_amdgcn_sched_barrier(0);                                           \
    const int tn = (t < cTM1 - 1) ? t + 1 : cTM1 - 1;                            \
    ZO0 = *(const f32x4*)(yW + ((size_t)(tn * 32 + b0)) * 2048 + zc);            \
    ZO1 = *(const f32x4*)(yW + ((size_t)(tn * 32 + b1)) * 2048 + zc);            \
    if (t < cTM1 - 1) SLOT_BARRIER(slots, nb, t + 1);                            \
  }

__global__ __launch_bounds__(512, 1) void k_dec_mfma(
    const float* __restrict__ yW, const __hip_bfloat16* __restrict__ Utd,
    const float* __restrict__ prev_h, const float* __restrict__ prev_c,
    __hip_bfloat16* __restrict__ hdec, __hip_bfloat16* __restrict__ decb,
    const float* __restrict__ clsW, __hip_bfloat16* __restrict__ clsWt,
    const float* __restrict__ src_h, const float* __restrict__ neg,
    float* __restrict__ outp,
    unsigned* slots) {
  __shared__ __hip_bfloat16 Hs[32][520];
  __shared__ __hip_bfloat16 Ho[32][36];
  __shared__ float tcv[32][33];
  __shared__ float hv_sh[512];
  __shared__ float sc_sh[128];
  __shared__ float red_sh[128];
  __shared__ __hip_bfloat16 As[8192];
  __shared__ __hip_bfloat16 Bs[8192];

  const int tid = threadIdx.x;
  const int lane = tid & 63;
  const int wv = tid >> 6;

  if (blockIdx.x >= 112) {
    // ---- GEMM group (144 blocks): own-bn clsWt convert, then slot-gated h-half ----
    const int k = blockIdx.x - 112;   // 0..143
#pragma unroll 1
    for (int pick = 0; pick < 2; ++pick) {
      int bn = k + pick * 144;
      if (bn >= 250) break;
      for (int by = 0; by < 32; ++by)
#pragma unroll 1
        for (int sub = 0; sub < 4; ++sub)
          f2bT_tile512(clsW, clsWt, 1024, 32000, bn * 4 + sub, by, tcv);
    }
    const int wr = wv >> 2, wc = wv & 3;
    const int fr = lane & 15, fq = lane >> 4;
#pragma unroll 1
    for (int tm = 0; tm < 16; ++tm) {
      unsigned need = (unsigned)(4 * tm + 4 > 63 ? 63 : 4 * tm + 4);
      if (wv == 0) {
        for (;;) {
          unsigned v = sc_loadu(slots + (lane & 15));
          if (__all((lane >= 16) | (v >= need))) break;
          __builtin_amdgcn_s_sleep(4);
        }
      }
      __syncthreads();
#pragma unroll 1
      for (int pick = 0; pick < 2; ++pick) {
        int bn = k + pick * 144;
        if (bn >= 250) break;
        f32x4 acc[4][2] = {};
        for (int kt = 0; kt < 512; kt += 64) {
          bf16x8 ar[2];
#pragma unroll
          for (int i = 0; i < 2; ++i) {
            int c = tid + i * 512;            // 0..1023 chunks of 8 bf16
            int row = c >> 3, ko = (c & 7) * 8;
            ar[i] = sc_load16(decb + (size_t)(tm * 128 + row) * 1024 + 512 + kt + ko);
          }
#pragma unroll
          for (int i = 0; i < 2; ++i) {
            int ch = wv * 2 + i;
            const __hip_bfloat16* gb = clsWt + (size_t)(bn * 128 + ch * 8 + (lane >> 3)) * 1024 + 512 + kt + (lane & 7) * 8;
            __builtin_amdgcn_global_load_lds(
                (const __attribute__((address_space(1))) uint32_t*)gb,
                (__attribute__((address_space(3))) uint32_t*)(Bs + ch * 512), 16, 0, 0);
          }
          asm volatile("s_waitcnt vmcnt(2)" ::: "memory");   // ar done (2 lds issues younger)
          __builtin_amdgcn_sched_barrier(0);
#pragma unroll
          for (int i = 0; i < 2; ++i) {
            int c = tid + i * 512;
            int row = c >> 3, ko = (c & 7) * 8;
            *(bf16x8*)&As[row * 64 + ko] = ar[i];
          }
          asm volatile("s_waitcnt vmcnt(0) lgkmcnt(0)" ::: "memory");
          __builtin_amdgcn_s_barrier();
          __builtin_amdgcn_sched_barrier(0);
#pragma unroll
          for (int kk = 0; kk < 64; kk += 32) {
            const int ko = kk + fq * 8;
            bf16x8 a[4], b[2];
#pragma unroll
            for (int m = 0; m < 4; ++m)
              a[m] = *(const bf16x8*)(As + (size_t)(wr * 64 + m * 16 + fr) * 64 + ko);
#pragma unroll
            for (int n = 0; n < 2; ++n)
              b[n] = *(const bf16x8*)(Bs + (size_t)(wc * 32 + n * 16 + fr) * 64 + ko);
#pragma unroll
            for (int m = 0; m < 4; ++m)
#pragma unroll
              for (int n = 0; n < 2; ++n)
                acc[m][n] = __builtin_amdgcn_mfma_f32_16x16x32_bf16(a[m], b[n], acc[m][n], 0, 0, 0);
          }
          __syncthreads();
        }
#pragma unroll
        for (int m = 0; m < 4; ++m) {
          const int row0 = tm * 128 + wr * 64 + m * 16 + fq * 4;
#pragma unroll
          for (int n = 0; n < 2; ++n) {
            const int col = bn * 128 + wc * 32 + n * 16 + fr;
#pragma unroll
            for (int r = 0; r < 4; ++r) {
              const int rrow = row0 + r;
              if (rrow < 2016) {
                int orow = (rrow & 31) * 63 + (rrow >> 5);
                outp[(size_t)orow * 32000 + col] = acc[m][n][r];
              }
            }
          }
        }
      }
    }
    return;
  }

  if (blockIdx.x >= 16) {
    // ---- attention group (96 blocks): slot-gated tasks ----
    const int sidx = blockIdx.x - 16;   // 0..95
    unsigned waited = 0;
    for (int i = sidx; i < 2016; i += 96) {
      int t = i >> 5, b = i & 31;
      unsigned need = (unsigned)(t + 1);
      if (need > waited) {
        if (wv == 0) {
          for (;;) {
            unsigned v = sc_loadu(slots + (lane & 15));
            if (__all((lane >= 16) | (v >= need))) break;
            __builtin_amdgcn_s_sleep(4);
          }
        }
        __syncthreads();
        waited = need;
      }
      attn_one(src_h, neg, decb, b, t, hv_sh, sc_sh, red_sh);
    }
    return;
  }

  const int nb = blockIdx.x;      // 0..15
  const int c0 = nb * 128;
  const int fr = lane & 15;
  const int fq = lane >> 4;

  bf16x8 afrag[16];
#pragma unroll
  for (int kk = 0; kk < 16; ++kk)
    afrag[kk] = *(const bf16x8*)(Utd + (size_t)(c0 + wv * 16 + fr) * 512 + kk * 32 + fq * 8);

  const int jglob = nb * 32 + wv * 4 + fq;
  const int jloc = wv * 4 + fq;
  const int b0 = fr, b1 = fr + 16;
  const int zc = c0 + wv * 16 + fq * 4;
  const int bb = tid >> 4, jp = (tid & 15) * 2;
  float cs0 = prev_c[(size_t)b0 * 512 + jglob];
  float cs1 = prev_c[(size_t)b1 * 512 + jglob];

  f32x4 zA0 = *(const f32x4*)(yW + ((size_t)b0) * 2048 + zc);
  f32x4 zA1 = *(const f32x4*)(yW + ((size_t)b1) * 2048 + zc);
  f32x4 zB0, zB1;

  for (int it = 0; it < 31; ++it) {
    DEC_STEP(2 * it, zA0, zA1, zB0, zB1);
    DEC_STEP(2 * it + 1, zB0, zB1, zA0, zA1);
  }
  DEC_STEP(62, zA0, zA1, zB0, zB1);
  // publish final generation (gen 63) for attention t=62 and h-half tm=15
  asm volatile("s_waitcnt vmcnt(0)" ::: "memory");
  __builtin_amdgcn_s_barrier();
  if (tid == 0) sc_storeu(slots + nb, (unsigned)cTM1);
}

extern "C" void kernel_launch(void* const* d_in, const int* in_sizes, int n_in,
                              void* d_out, int out_size, void* d_ws, size_t ws_size,
                              hipStream_t stream) {
  const int* src = (const int*)d_in[0];
  const int* trg = (const int*)d_in[1];
  const float* E_src = (const float*)d_in[2];
  const float* E_trg = (const float*)d_in[3];
  const float* Wf = (const float*)d_in[4];
  const float* Uf = (const float*)d_in[5];
  const float* bf = (const float*)d_in[6];
  const float* Wb = (const float*)d_in[7];
  const float* Ub = (const float*)d_in[8];
  const float* bb = (const float*)d_in[9];
  const float* Wd = (const float*)d_in[10];
  const float* Ud = (const float*)d_in[11];
  const float* bd = (const float*)d_in[12];
  const float* fcW = (const float*)d_in[13];
  const float* fcb = (const float*)d_in[14];
  const float* clsW = (const float*)d_in[15];
  const float* clsb = (const float*)d_in[16];
  float* out = (float*)d_out;
  float* ws = (float*)d_ws;

  // ---- static layout (float offsets) ----
  float* xWf = ws;                                           // 8388608
  float* xWb = ws + 8388608;                                 // -> 16777216
  float* yW = ws + 16777216;                                 // 2048x2048 -> 20971520 (+gap)
  float* neg = ws + 23035904;                                // -> 23040000
  float* fco = ws + 23040000;                                // 2129920 -> 25169920
  __hip_bfloat16* decb = (__hip_bfloat16*)(ws + 25169920);   // 2048x1024 bf16, t-major rows
  __hip_bfloat16* Utd = (__hip_bfloat16*)(ws + 26218496);    // -> 26742784
  __hip_bfloat16* henc = (__hip_bfloat16*)(ws + 26742784);   // -> 26808320
  __hip_bfloat16* hdec = (__hip_bfloat16*)(ws + 26808320);   // -> 26841088
  unsigned* bars = (unsigned*)(ws + 26841088);               // 64 uints -> 26841152
  float* pool = ws + 26841152;

  // pool transients (pre-encoder)
  __hip_bfloat16* xs_bf = (__hip_bfloat16*)pool;              // 1048576 fl
  __hip_bfloat16* ys_bf = (__hip_bfloat16*)(pool + 1048576);  // 524288 fl
  __hip_bfloat16* Utf = (__hip_bfloat16*)(pool + 1572864);    // 524288 fl
  __hip_bfloat16* Utb = (__hip_bfloat16*)(pool + 2097152);    // 524288 fl -> 2621440
  __hip_bfloat16* Wtfx = (__hip_bfloat16*)(pool + 2621440);   // 524288 fl
  __hip_bfloat16* Wtbx = (__hip_bfloat16*)(pool + 3145728);   // 524288 fl
  __hip_bfloat16* Wtdx = (__hip_bfloat16*)(pool + 3670016);   // 524288 fl
  float* bfx = pool + 4194304;                                // 2048
  float* bbx = pool + 4196352;                                // 2048
  float* bdx = pool + 4198400;                                // 2048 -> 4200448
  __hip_bfloat16* fcWt = (__hip_bfloat16*)(pool + 4200448);   // 262144 fl -> 4462592
  __hip_bfloat16* cat_bf = (__hip_bfloat16*)(pool + 4462592); // 4224x1024 bf16 -> 6625280
  __hip_bfloat16* clsWt = (__hip_bfloat16*)xWf;               // 32000x1024 bf16 (xWf/xWb dead post-encoder)

  // phase A: mega-prep (weights + biases + embeds + pads + barrier init)
  k_prep<<<9833, 256, 0, stream>>>(Wf, Wb, Wd, Uf, Ub, Ud, fcW, bf, bb, bd,
                                   src, trg, E_src, E_trg,
                                   Wtfx, Wtbx, Wtdx, Utf, Utb, Utd, fcWt,
                                   bfx, bbx, bdx, xs_bf, ys_bf, neg, cat_bf, bars);

  // encoder input projections (one launch, z = {fwd,bwd})
  k_bgemm2<<<dim3(32, 16, 2), 256, 0, stream>>>(xs_bf, Wtfx, Wtbx, bfx, bbx,
                                                xWf, xWb, 4096, 512, 2048);

  // phase B: persistent MFMA encoder (+ yW projection in side blocks)
  k_enc_mfma<<<256, 512, 0, stream>>>(xWf, xWb, Utf, Utb, cat_bf, henc, bars,
                                      ys_bf, Wtdx, bdx, yW);

  // phase C: fc projection (cat rows fully written by encoder)
  k_bgemm<<<dim3(33, 4), 256, 0, stream>>>(cat_bf, fcWt, fcb, fco, 4160, 1024, 512);

  // phase D: persistent MFMA decoder; side blocks: attention + clsW convert + h-half classifier
  const float* prev_h = fco + (size_t)4096 * 512;
  const float* prev_c = fco + (size_t)4128 * 512;
  k_dec_mfma<<<256, 512, 0, stream>>>(yW, Utd, prev_h, prev_c, hdec, decb,
                                      clsW, clsWt, fco, neg, out, bars + 32);

  // phase F: classifier ws-half (adds onto h-half partials + bias)
  k_bgemm_ws<<<dim3(16, 250), 256, 0, stream>>>(decb, clsWt, clsb, out);
}

// Round 18
// 1145.993 us; speedup vs baseline: 1.3248x; 1.3248x over previous
//
#include <hip/hip_runtime.h>
#include <hip/hip_bf16.h>
#include <stdint.h>
#include <string.h>

constexpr int cB = 32, cS = 128, cT = 64, cH = 512, cH4 = 2048, cVT = 32000, cTM1 = 63;

typedef __attribute__((ext_vector_type(8))) __bf16 bf16x8;
typedef __attribute__((ext_vector_type(4))) float f32x4;

__device__ __forceinline__ float sigm(float x) { return 1.0f / (1.0f + expf(-x)); }

// ---- coherence-point (L3) bypass ops: cross-XCD visible without fences ----
__device__ __forceinline__ bf16x8 sc_load16(const __hip_bfloat16* p) {
  bf16x8 r;
  asm volatile("global_load_dwordx4 %0, %1, off sc0 sc1"
               : "=&v"(r) : "v"(p) : "memory");
  return r;
}
__device__ __forceinline__ unsigned sc_load4u(const __hip_bfloat16* p) {
  unsigned r;
  asm volatile("global_load_dword %0, %1, off sc0 sc1"
               : "=&v"(r) : "v"(p) : "memory");
  return r;
}
__device__ __forceinline__ void sc_store4(__hip_bfloat16* p, unsigned v) {
  asm volatile("global_store_dword %0, %1, off sc0 sc1"
               :: "v"(p), "v"(v) : "memory");
}
__device__ __forceinline__ void pl_store4(__hip_bfloat16* p, unsigned v) {
  asm volatile("global_store_dword %0, %1, off"
               :: "v"(p), "v"(v) : "memory");
}
__device__ __forceinline__ unsigned sc_loadu(const unsigned* p) {
  unsigned r;
  asm volatile("global_load_dword %0, %1, off sc0 sc1"
               : "=&v"(r) : "v"(p) : "memory");
  asm volatile("s_waitcnt vmcnt(0)" ::: "memory");
  return r;
}
__device__ __forceinline__ void sc_storeu(unsigned* p, unsigned v) {
  asm volatile("global_store_dword %0, %1, off sc0 sc1"
               :: "v"(p), "v"(v) : "memory");
}

// ---------------- f2bT tile helper (256 threads): fp32 [K][N] tile -> bf16 [N][K] ----------------
__device__ __forceinline__ void f2bT_tile(const float* __restrict__ src,
                                          __hip_bfloat16* __restrict__ dst,
                                          int K, int N, int gi, int bx, int by,
                                          float (*t)[33]) {
  int nt = bx * 32, kt = by * 32;
  int c = threadIdx.x & 31, r0 = threadIdx.x >> 5;
#pragma unroll
  for (int i = 0; i < 4; ++i) {
    int r = r0 + i * 8;
    t[r][c] = src[(size_t)(kt + r) * N + nt + c];
  }
  __syncthreads();
#pragma unroll
  for (int i = 0; i < 4; ++i) {
    int row = nt + r0 + i * 8;
    int pr = gi ? (((row & 511) << 2) | (row >> 9)) : row;
    dst[(size_t)pr * K + kt + c] = __float2bfloat16(t[c][r0 + i * 8]);
  }
  __syncthreads();
}

// 512-thread variant (decoder side blocks)
__device__ __forceinline__ void f2bT_tile512(const float* __restrict__ src,
                                             __hip_bfloat16* __restrict__ dst,
                                             int K, int N, int bx, int by,
                                             float (*t)[33]) {
  int nt = bx * 32, kt = by * 32;
  int c = threadIdx.x & 31, r0 = (threadIdx.x >> 5) & 15;
#pragma unroll
  for (int i = 0; i < 2; ++i) {
    int r = r0 + i * 16;
    t[r][c] = src[(size_t)(kt + r) * N + nt + c];
  }
  __syncthreads();
#pragma unroll
  for (int i = 0; i < 2; ++i) {
    int row = nt + r0 + i * 16;
    dst[(size_t)row * K + kt + c] = __float2bfloat16(t[c][r0 + i * 16]);
  }
  __syncthreads();
}

// ---------------- mega-prep: weights + biases + embeds + pads + barrier init ----------------
__global__ __launch_bounds__(256) void k_prep(
    const float* __restrict__ Wf, const float* __restrict__ Wb, const float* __restrict__ Wd,
    const float* __restrict__ Uf, const float* __restrict__ Ub, const float* __restrict__ Ud,
    const float* __restrict__ fcW,
    const float* __restrict__ bf, const float* __restrict__ bb, const float* __restrict__ bd,
    const int* __restrict__ src, const int* __restrict__ trg,
    const float* __restrict__ E_src, const float* __restrict__ E_trg,
    __hip_bfloat16* __restrict__ Wtfx, __hip_bfloat16* __restrict__ Wtbx,
    __hip_bfloat16* __restrict__ Wtdx,
    __hip_bfloat16* __restrict__ Utf, __hip_bfloat16* __restrict__ Utb,
    __hip_bfloat16* __restrict__ Utd,
    __hip_bfloat16* __restrict__ fcWt,
    float* __restrict__ bfx, float* __restrict__ bbx, float* __restrict__ bdx,
    __hip_bfloat16* __restrict__ xs_bf, __hip_bfloat16* __restrict__ ys_bf,
    float* __restrict__ neg, __hip_bfloat16* __restrict__ catb,
    unsigned* __restrict__ bars) {
  __shared__ float t[32][33];
  int id = blockIdx.x;
  int tid = threadIdx.x;
  if (id < 6144) {
    int grp = id >> 10, r = id & 1023;
    const float* s; __hip_bfloat16* d;
    switch (grp) {
      case 0: s = Wf; d = Wtfx; break;
      case 1: s = Wb; d = Wtbx; break;
      case 2: s = Wd; d = Wtdx; break;
      case 3: s = Uf; d = Utf; break;
      case 4: s = Ub; d = Utb; break;
      default: s = Ud; d = Utd; break;
    }
    f2bT_tile(s, d, 512, 2048, 1, r & 63, r >> 6, t);
  } else if (id < 6656) {
    int r = id - 6144;
    f2bT_tile(fcW, fcWt, 1024, 512, 0, r & 15, r >> 4, t);
  } else if (id < 6680) {
    int r = id - 6656;
    const float* s = (r < 8) ? bf : ((r < 16) ? bb : bd);
    float* d = (r < 8) ? bfx : ((r < 16) ? bbx : bdx);
    int i = (r & 7) * 256 + tid;
    d[i] = s[(i & 3) * 512 + (i >> 2)];
  } else if (id < 6744) {
    int r = id - 6680;                        // ys zero-pad rows 2016..2047
    ys_bf[(size_t)2016 * 512 + r * 256 + tid] = __float2bfloat16(0.0f);
  } else if (id < 6776) {
    int r = id - 6744;                        // cat zero rows 4160..4223
    __hip_bfloat16* d = catb + (size_t)4160 * 1024 + (size_t)r * 2048 + tid * 8;
    bf16x8 zv = {};
    *(bf16x8*)d = zv;
  } else if (id < 8824) {
    int r = id - 6776;                        // src embed: rows 2r, 2r+1
    int half = tid >> 7, sb = 2 * r + half;
    int s = sb >> 5, b = sb & 31;
    int tok = src[b * cS + s];
    int cg = tid & 127;
    float4 e = ((const float4*)(E_src + (size_t)tok * cH))[cg];
    __hip_bfloat16* drow = xs_bf + (size_t)sb * cH + cg * 4;
    drow[0] = __float2bfloat16(e.x); drow[1] = __float2bfloat16(e.y);
    drow[2] = __float2bfloat16(e.z); drow[3] = __float2bfloat16(e.w);
    if (cg == 0) neg[b * cS + s] = (tok == 0) ? -1e9f : 0.0f;
  } else if (id < 9832) {
    int r = id - 8824;                        // trg embed: rows 2r, 2r+1
    int half = tid >> 7, tb = 2 * r + half;
    int tt = tb >> 5, b = tb & 31;
    int tok = trg[b * cT + tt];
    int cg = tid & 127;
    float4 e = ((const float4*)(E_trg + (size_t)tok * cH))[cg];
    __hip_bfloat16* drow = ys_bf + (size_t)tb * cH + cg * 4;
    drow[0] = __float2bfloat16(e.x); drow[1] = __float2bfloat16(e.y);
    drow[2] = __float2bfloat16(e.z); drow[3] = __float2bfloat16(e.w);
  } else {
    if (tid < 64) bars[tid] = 0u;             // barrier slots
  }
}

// ---------------- bf16 MFMA GEMM: C[M,N] = A[M,K] @ Bt[N,K]^T + bias ----------------
__global__ __launch_bounds__(256) void k_bgemm(const __hip_bfloat16* __restrict__ A,
                                               const __hip_bfloat16* __restrict__ Bt,
                                               const float* __restrict__ bias,
                                               float* __restrict__ C,
                                               int M, int K, int N) {
  __shared__ __hip_bfloat16 As[128 * 64];
  __shared__ __hip_bfloat16 Bs[128 * 64];
  const int tid = threadIdx.x;
  const int lane = tid & 63;
  const int wave = tid >> 6;
  const int wr = wave >> 1, wc = wave & 1;
  const int bm = blockIdx.x * 128, bn = blockIdx.y * 128;

  f32x4 acc[4][4] = {};

  const int srow = lane >> 3;
  const int scol = (lane & 7) * 8;

  for (int kt = 0; kt < K; kt += 64) {
#pragma unroll
    for (int i = 0; i < 4; ++i) {
      int c = wave * 4 + i;
      const __hip_bfloat16* ga = A + (size_t)(bm + c * 8 + srow) * K + kt + scol;
      __builtin_amdgcn_global_load_lds(
          (const __attribute__((address_space(1))) uint32_t*)ga,
          (__attribute__((address_space(3))) uint32_t*)(As + c * 512), 16, 0, 0);
      const __hip_bfloat16* gb = Bt + (size_t)(bn + c * 8 + srow) * K + kt + scol;
      __builtin_amdgcn_global_load_lds(
          (const __attribute__((address_space(1))) uint32_t*)gb,
          (__attribute__((address_space(3))) uint32_t*)(Bs + c * 512), 16, 0, 0);
    }
    __syncthreads();

#pragma unroll
    for (int kk = 0; kk < 64; kk += 32) {
      const int ko = kk + (lane >> 4) * 8;
      bf16x8 a[4], b[4];
      const int ar = wr * 64 + (lane & 15);
#pragma unroll
      for (int m = 0; m < 4; ++m)
        a[m] = *(const bf16x8*)(As + (size_t)(ar + m * 16) * 64 + ko);
      const int br = wc * 64 + (lane & 15);
#pragma unroll
      for (int n = 0; n < 4; ++n)
        b[n] = *(const bf16x8*)(Bs + (size_t)(br + n * 16) * 64 + ko);
#pragma unroll
      for (int m = 0; m < 4; ++m)
#pragma unroll
        for (int n = 0; n < 4; ++n)
          acc[m][n] = __builtin_amdgcn_mfma_f32_16x16x32_bf16(a[m], b[n], acc[m][n], 0, 0, 0);
    }
    __syncthreads();
  }

#pragma unroll
  for (int m = 0; m < 4; ++m) {
    const int row0 = bm + wr * 64 + m * 16 + (lane >> 4) * 4;
#pragma unroll
    for (int n = 0; n < 4; ++n) {
      const int col = bn + wc * 64 + n * 16 + (lane & 15);
      const float bv = bias[col];
#pragma unroll
      for (int r = 0; r < 4; ++r) {
        const int row = row0 + r;
        if (row < M) C[(size_t)row * N + col] = acc[m][n][r] + bv;
      }
    }
  }
}

// z-merged variant for the two encoder input projections
__global__ __launch_bounds__(256) void k_bgemm2(
    const __hip_bfloat16* __restrict__ A,
    const __hip_bfloat16* __restrict__ Bt0, const __hip_bfloat16* __restrict__ Bt1,
    const float* __restrict__ bias0, const float* __restrict__ bias1,
    float* __restrict__ C0, float* __restrict__ C1,
    int M, int K, int N) {
  const __hip_bfloat16* Bt = blockIdx.z ? Bt1 : Bt0;
  const float* bias = blockIdx.z ? bias1 : bias0;
  float* C = blockIdx.z ? C1 : C0;

  __shared__ __hip_bfloat16 As[128 * 64];
  __shared__ __hip_bfloat16 Bs[128 * 64];
  const int tid = threadIdx.x;
  const int lane = tid & 63;
  const int wave = tid >> 6;
  const int wr = wave >> 1, wc = wave & 1;
  const int bm = blockIdx.x * 128, bn = blockIdx.y * 128;

  f32x4 acc[4][4] = {};
  const int srow = lane >> 3;
  const int scol = (lane & 7) * 8;

  for (int kt = 0; kt < K; kt += 64) {
#pragma unroll
    for (int i = 0; i < 4; ++i) {
      int c = wave * 4 + i;
      const __hip_bfloat16* ga = A + (size_t)(bm + c * 8 + srow) * K + kt + scol;
      __builtin_amdgcn_global_load_lds(
          (const __attribute__((address_space(1))) uint32_t*)ga,
          (__attribute__((address_space(3))) uint32_t*)(As + c * 512), 16, 0, 0);
      const __hip_bfloat16* gb = Bt + (size_t)(bn + c * 8 + srow) * K + kt + scol;
      __builtin_amdgcn_global_load_lds(
          (const __attribute__((address_space(1))) uint32_t*)gb,
          (__attribute__((address_space(3))) uint32_t*)(Bs + c * 512), 16, 0, 0);
    }
    __syncthreads();
#pragma unroll
    for (int kk = 0; kk < 64; kk += 32) {
      const int ko = kk + (lane >> 4) * 8;
      bf16x8 a[4], b[4];
      const int ar = wr * 64 + (lane & 15);
#pragma unroll
      for (int m = 0; m < 4; ++m)
        a[m] = *(const bf16x8*)(As + (size_t)(ar + m * 16) * 64 + ko);
      const int br = wc * 64 + (lane & 15);
#pragma unroll
      for (int n = 0; n < 4; ++n)
        b[n] = *(const bf16x8*)(Bs + (size_t)(br + n * 16) * 64 + ko);
#pragma unroll
      for (int m = 0; m < 4; ++m)
#pragma unroll
        for (int n = 0; n < 4; ++n)
          acc[m][n] = __builtin_amdgcn_mfma_f32_16x16x32_bf16(a[m], b[n], acc[m][n], 0, 0, 0);
    }
    __syncthreads();
  }
#pragma unroll
  for (int m = 0; m < 4; ++m) {
    const int row0 = bm + wr * 64 + m * 16 + (lane >> 4) * 4;
#pragma unroll
    for (int n = 0; n < 4; ++n) {
      const int col = bn + wc * 64 + n * 16 + (lane & 15);
      const float bv = bias[col];
#pragma unroll
      for (int r = 0; r < 4; ++r) {
        const int row = row0 + r;
        if (row < M) C[(size_t)row * N + col] = acc[m][n][r] + bv;
      }
    }
  }
}

// ---- slot-array grid barrier (16 blocks): fire-and-forget arrive + wave0 ballot poll ----
#define SLOT_BARRIER(SLOTS, NB, GEN)                                             \
  {                                                                              \
    asm volatile("s_waitcnt vmcnt(2)" ::: "memory");                             \
    __builtin_amdgcn_sched_barrier(0);                                           \
    __builtin_amdgcn_s_barrier();                                                \
    if (tid == 0) sc_storeu((SLOTS) + (NB), (unsigned)(GEN));                    \
    if (wv == 0) {                                                               \
      for (;;) {                                                                 \
        unsigned v = sc_loadu((SLOTS) + (lane & 15));                            \
        if (__all((lane >= 16) | (v >= (unsigned)(GEN)))) break;                 \
        __builtin_amdgcn_s_sleep(1);                                             \
      }                                                                          \
    }                                                                            \
    __builtin_amdgcn_s_barrier();                                                \
    __builtin_amdgcn_sched_barrier(0);                                           \
  }

// ================= persistent MFMA encoder: blocks 0-31 recurrence (16/dir, 512 thr),
// blocks 32-255: yW projection (writes disjoint from xWf/xWb!) =================
#define ENC_STEP(T, ZI0, ZI1, ZO0, ZO1)                                          \
  {                                                                              \
    const int t = (T);                                                           \
    const int trow = dir ? (127 - t) : t;                                        \
    if (t > 0) {                                                                 \
      const __hip_bfloat16* hsrc = hcur + (size_t)((t + 1) & 1) * 16384;         \
      bf16x8 hr[4];                                                              \
      _Pragma("unroll")                                                          \
      for (int i = 0; i < 4; ++i) {                                              \
        int c = tid + i * 512;                                                   \
        hr[i] = sc_load16(hsrc + (size_t)c * 8);                                 \
      }                                                                          \
      asm volatile("s_waitcnt vmcnt(0)" ::: "memory");                           \
      __builtin_amdgcn_sched_barrier(0);                                         \
      _Pragma("unroll")                                                          \
      for (int i = 0; i < 4; ++i) {                                              \
        int c = tid + i * 512;                                                   \
        int r = c >> 6, cc = (c & 63) * 8;                                       \
        *(bf16x8*)&Hs[r][cc] = hr[i];                                            \
      }                                                                          \
      asm volatile("s_waitcnt lgkmcnt(0)" ::: "memory");                         \
      __builtin_amdgcn_s_barrier();                                              \
      __builtin_amdgcn_sched_barrier(0);                                         \
    }                                                                            \
    f32x4 acc0 = {}, acc1 = {};                                                  \
    if (t > 0) {                                                                 \
      _Pragma("unroll")                                                          \
      for (int kk = 0; kk < 16; ++kk) {                                          \
        bf16x8 h0v = *(const bf16x8*)&Hs[b0][kk * 32 + fq * 8];                  \
        bf16x8 h1v = *(const bf16x8*)&Hs[b1][kk * 32 + fq * 8];                  \
        acc0 = __builtin_amdgcn_mfma_f32_16x16x32_bf16(afrag[kk], h0v, acc0, 0, 0, 0); \
        acc1 = __builtin_amdgcn_mfma_f32_16x16x32_bf16(afrag[kk], h1v, acc1, 0, 0, 0); \
      }                                                                          \
    }                                                                            \
    {                                                                            \
      float zi = ZI0[0] + acc0[0], zf = ZI0[1] + acc0[1],                        \
            zg = ZI0[2] + acc0[2], zo = ZI0[3] + acc0[3];                        \
      cs0 = sigm(zf) * cs0 + sigm(zi) * tanhf(zg);                               \
      Ho[b0][jloc] = __float2bfloat16(sigm(zo) * tanhf(cs0));                    \
    }                                                                            \
    {                                                                            \
      float zi = ZI1[0] + acc1[0], zf = ZI1[1] + acc1[1],                        \
            zg = ZI1[2] + acc1[2], zo = ZI1[3] + acc1[3];                        \
      cs1 = sigm(zf) * cs1 + sigm(zi) * tanhf(zg);                               \
      Ho[b1][jloc] = __float2bfloat16(sigm(zo) * tanhf(cs1));                    \
    }                                                                            \
    asm volatile("s_waitcnt lgkmcnt(0)" ::: "memory");                           \
    __builtin_amdgcn_s_barrier();                                                \
    __builtin_amdgcn_sched_barrier(0);                                           \
    {                                                                            \
      unsigned v = *(const unsigned*)&Ho[bb][jp];                                \
      sc_store4(hcur + (size_t)(t & 1) * 16384 + (size_t)bb * 512 + nb * 32 + jp, v); \
      pl_store4(catb + ((size_t)(bb * 128 + trow)) * 1024 + dhalf + nb * 32 + jp, v); \
    }                                                                            \
    __builtin_amdgcn_sched_barrier(0);                                           \
    const int tn = (t < 127) ? t + 1 : 127;                                      \
    const int ntrow = dir ? (127 - tn) : tn;                                     \
    ZO0 = *(const f32x4*)(xW + ((size_t)(ntrow * 32 + b0)) * 2048 + zc);         \
    ZO1 = *(const f32x4*)(xW + ((size_t)(ntrow * 32 + b1)) * 2048 + zc);         \
    if (t < 127) SLOT_BARRIER(slots, nb, t + 1);                                 \
  }

__global__ __launch_bounds__(512, 1) void k_enc_mfma(
    const float* __restrict__ xWf, const float* __restrict__ xWb,
    const __hip_bfloat16* __restrict__ Utf, const __hip_bfloat16* __restrict__ Utb,
    __hip_bfloat16* __restrict__ catb,
    __hip_bfloat16* __restrict__ henc,
    unsigned* bars,
    const __hip_bfloat16* __restrict__ ys_bf, const __hip_bfloat16* __restrict__ Wtdx,
    const float* __restrict__ bdx, float* __restrict__ yW) {
  __shared__ __hip_bfloat16 Hs[32][520];
  __shared__ __hip_bfloat16 Ho[32][36];
  __shared__ __hip_bfloat16 As[8192];
  __shared__ __hip_bfloat16 Bs[8192];

  const int tid = threadIdx.x;
  const int lane = tid & 63;
  const int wv = tid >> 6;                  // 0..7

  if (blockIdx.x >= 32) {
    // ---- yW projection: [2048 x 512] @ Wtdx^T -> [2048 x 2048], 256 tiles / 224 blocks ----
    const int sidx = blockIdx.x - 32;
    const int wr = wv >> 2, wc = wv & 3;
    const int fr = lane & 15, fq = lane >> 4;
    for (int tile = sidx; tile < 256; tile += 224) {
      int bm = (tile & 15) * 128, bn = (tile >> 4) * 128;
      f32x4 acc[4][2] = {};
      for (int kt = 0; kt < 512; kt += 64) {
#pragma unroll
        for (int i = 0; i < 2; ++i) {
          int ch = wv * 2 + i;
          const __hip_bfloat16* ga = ys_bf + (size_t)(bm + ch * 8 + (lane >> 3)) * 512 + kt + (lane & 7) * 8;
          __builtin_amdgcn_global_load_lds(
              (const __attribute__((address_space(1))) uint32_t*)ga,
              (__attribute__((address_space(3))) uint32_t*)(As + ch * 512), 16, 0, 0);
          const __hip_bfloat16* gb = Wtdx + (size_t)(bn + ch * 8 + (lane >> 3)) * 512 + kt + (lane & 7) * 8;
          __builtin_amdgcn_global_load_lds(
              (const __attribute__((address_space(1))) uint32_t*)gb,
              (__attribute__((address_space(3))) uint32_t*)(Bs + ch * 512), 16, 0, 0);
        }
        __syncthreads();
#pragma unroll
        for (int kk = 0; kk < 64; kk += 32) {
          const int ko = kk + fq * 8;
          bf16x8 a[4], b[2];
#pragma unroll
          for (int m = 0; m < 4; ++m)
            a[m] = *(const bf16x8*)(As + (size_t)(wr * 64 + m * 16 + fr) * 64 + ko);
#pragma unroll
          for (int n = 0; n < 2; ++n)
            b[n] = *(const bf16x8*)(Bs + (size_t)(wc * 32 + n * 16 + fr) * 64 + ko);
#pragma unroll
          for (int m = 0; m < 4; ++m)
#pragma unroll
            for (int n = 0; n < 2; ++n)
              acc[m][n] = __builtin_amdgcn_mfma_f32_16x16x32_bf16(a[m], b[n], acc[m][n], 0, 0, 0);
        }
        __syncthreads();
      }
#pragma unroll
      for (int m = 0; m < 4; ++m) {
        const int row0 = bm + wr * 64 + m * 16 + fq * 4;
#pragma unroll
        for (int n = 0; n < 2; ++n) {
          const int col = bn + wc * 32 + n * 16 + fr;
          const float bv = bdx[col];
#pragma unroll
          for (int r = 0; r < 4; ++r)
            yW[(size_t)(row0 + r) * 2048 + col] = acc[m][n][r] + bv;
        }
      }
    }
    return;
  }

  const int bid = blockIdx.x;
  const int dir = bid >> 4, nb = bid & 15;
  const int c0 = nb * 128;
  const float* xW = dir ? xWb : xWf;
  const __hip_bfloat16* Ut = dir ? Utb : Utf;
  const int dhalf = dir * 512;
  __hip_bfloat16* hcur = henc + (size_t)dir * 32768;   // [2][32][512] bf16
  unsigned* slots = bars + dir * 16;

  const int fr = lane & 15;
  const int fq = lane >> 4;

  bf16x8 afrag[16];
#pragma unroll
  for (int kk = 0; kk < 16; ++kk)
    afrag[kk] = *(const bf16x8*)(Ut + (size_t)(c0 + wv * 16 + fr) * 512 + kk * 32 + fq * 8);

  const int jloc = wv * 4 + fq;             // 0..31
  const int b0 = fr, b1 = fr + 16;
  const int zc = c0 + wv * 16 + fq * 4;
  const int bb = tid >> 4, jp = (tid & 15) * 2;   // coalesced 64B-row store mapping
  float cs0 = 0.f, cs1 = 0.f;

  const int trow0 = dir ? 127 : 0;
  f32x4 zA0 = *(const f32x4*)(xW + ((size_t)(trow0 * 32 + b0)) * 2048 + zc);
  f32x4 zA1 = *(const f32x4*)(xW + ((size_t)(trow0 * 32 + b1)) * 2048 + zc);
  f32x4 zB0, zB1;

  for (int it = 0; it < 64; ++it) {
    ENC_STEP(2 * it, zA0, zA1, zB0, zB1);
    ENC_STEP(2 * it + 1, zB0, zB1, zA0, zA1);
  }

  // ---- epilogue: final h row (4096+b) + c row (4128+b) straight into cat ----
  {
    unsigned v = *(const unsigned*)&Ho[bb][jp];   // Ho still holds t=127 h
    pl_store4(catb + (size_t)(4096 + bb) * 1024 + dhalf + nb * 32 + jp, v);
  }
  __syncthreads();
  Ho[b0][jloc] = __float2bfloat16(cs0);
  Ho[b1][jloc] = __float2bfloat16(cs1);
  asm volatile("s_waitcnt lgkmcnt(0)" ::: "memory");
  __builtin_amdgcn_s_barrier();
  {
    unsigned v = *(const unsigned*)&Ho[bb][jp];
    pl_store4(catb + (size_t)(4128 + bb) * 1024 + dhalf + nb * 32 + jp, v);
  }
}

// ---------------- 512-thread attention for one (b,t) ----------------
__device__ void attn_one(const float* __restrict__ src_h, const float* __restrict__ neg,
                         __hip_bfloat16* __restrict__ decb, int b, int t,
                         float* hv, float* sc, float* red) {
  const int tx = threadIdx.x;
  __hip_bfloat16* drow = decb + ((size_t)b * cTM1 + t) * 1024;
  if (tx < 256) {
    unsigned u = sc_load4u(drow + 512 + tx * 2);
    asm volatile("s_waitcnt vmcnt(0)" ::: "memory");
    hv[tx * 2] = __uint_as_float(u << 16);
    hv[tx * 2 + 1] = __uint_as_float(u & 0xffff0000u);
  }
  __syncthreads();
  {
    int s = tx >> 2, q = tx & 3;
    const float4* sr = (const float4*)(src_h + ((size_t)b * cS + s) * cH + q * 128);
    const float4* hh = (const float4*)(hv + q * 128);
    float acc = 0.f;
#pragma unroll 8
    for (int k = 0; k < 32; ++k) {
      float4 v = sr[k], h4 = hh[k];
      acc += v.x * h4.x + v.y * h4.y + v.z * h4.z + v.w * h4.w;
    }
    acc += __shfl_xor(acc, 1);
    acc += __shfl_xor(acc, 2);
    if (q == 0) {
      float s0 = acc + neg[b * cS + s];
      sc[s] = s0;
      red[s] = s0;
    }
  }
  __syncthreads();
  for (int off = 64; off >= 1; off >>= 1) {
    if (tx < off) red[tx] = fmaxf(red[tx], red[tx + off]);
    __syncthreads();
  }
  float mx = red[0];
  __syncthreads();
  float e = 0.f;
  if (tx < cS) { e = expf(sc[tx] - mx); red[tx] = e; }
  __syncthreads();
  for (int off = 64; off >= 1; off >>= 1) {
    if (tx < off) red[tx] += red[tx + off];
    __syncthreads();
  }
  float inv = 1.0f / red[0];
  __syncthreads();
  if (tx < cS) sc[tx] = e * inv;
  __syncthreads();
  {
    float a = 0.f;
    const float* sr = src_h + (size_t)b * cS * cH + tx;
    for (int s = 0; s < cS; ++s) a += sc[s] * sr[(size_t)s * cH];
    drow[tx] = __float2bfloat16(a);
  }
}

// ================= persistent MFMA decoder: blocks 0-15 recurrence,
// blocks 16-255: clsW convert + slot-gated attention =================
#define DEC_STEP(T, ZI0, ZI1, ZO0, ZO1)                                          \
  {                                                                              \
    const int t = (T);                                                           \
    if (t == 0) {                                                                \
      const float4* ph4 = (const float4*)prev_h;                                 \
      _Pragma("unroll")                                                          \
      for (int i = 0; i < 8; ++i) {                                              \
        int c = tid + i * 512;                                                   \
        float4 v = ph4[c];                                                       \
        int r = c >> 7, c4 = (c & 127) * 4;                                      \
        Hs[r][c4 + 0] = __float2bfloat16(v.x);                                   \
        Hs[r][c4 + 1] = __float2bfloat16(v.y);                                   \
        Hs[r][c4 + 2] = __float2bfloat16(v.z);                                   \
        Hs[r][c4 + 3] = __float2bfloat16(v.w);                                   \
      }                                                                          \
    } else {                                                                     \
      const __hip_bfloat16* hsrc = hdec + (size_t)((t + 1) & 1) * 16384;         \
      bf16x8 hr[4];                                                              \
      _Pragma("unroll")                                                          \
      for (int i = 0; i < 4; ++i) {                                              \
        int c = tid + i * 512;                                                   \
        hr[i] = sc_load16(hsrc + (size_t)c * 8);                                 \
      }                                                                          \
      asm volatile("s_waitcnt vmcnt(0)" ::: "memory");                           \
      __builtin_amdgcn_sched_barrier(0);                                         \
      _Pragma("unroll")                                                          \
      for (int i = 0; i < 4; ++i) {                                              \
        int c = tid + i * 512;                                                   \
        int r = c >> 6, cc = (c & 63) * 8;                                       \
        *(bf16x8*)&Hs[r][cc] = hr[i];                                            \
      }                                                                          \
    }                                                                            \
    asm volatile("s_waitcnt lgkmcnt(0)" ::: "memory");                           \
    __builtin_amdgcn_s_barrier();                                                \
    __builtin_amdgcn_sched_barrier(0);                                           \
    f32x4 acc0 = {}, acc1 = {};                                                  \
    _Pragma("unroll")                                                            \
    for (int kk = 0; kk < 16; ++kk) {                                            \
      bf16x8 h0v = *(const bf16x8*)&Hs[b0][kk * 32 + fq * 8];                    \
      bf16x8 h1v = *(const bf16x8*)&Hs[b1][kk * 32 + fq * 8];                    \
      acc0 = __builtin_amdgcn_mfma_f32_16x16x32_bf16(afrag[kk], h0v, acc0, 0, 0, 0); \
      acc1 = __builtin_amdgcn_mfma_f32_16x16x32_bf16(afrag[kk], h1v, acc1, 0, 0, 0); \
    }                                                                            \
    {                                                                            \
      float zi = ZI0[0] + acc0[0], zf = ZI0[1] + acc0[1],                        \
            zg = ZI0[2] + acc0[2], zo = ZI0[3] + acc0[3];                        \
      cs0 = sigm(zf) * cs0 + sigm(zi) * tanhf(zg);                               \
      Ho[b0][jloc] = __float2bfloat16(sigm(zo) * tanhf(cs0));                    \
    }                                                                            \
    {                                                                            \
      float zi = ZI1[0] + acc1[0], zf = ZI1[1] + acc1[1],                        \
            zg = ZI1[2] + acc1[2], zo = ZI1[3] + acc1[3];                        \
      cs1 = sigm(zf) * cs1 + sigm(zi) * tanhf(zg);                               \
      Ho[b1][jloc] = __float2bfloat16(sigm(zo) * tanhf(cs1));                    \
    }                                                                            \
    asm volatile("s_waitcnt lgkmcnt(0)" ::: "memory");                           \
    __builtin_amdgcn_s_barrier();                                                \
    __builtin_amdgcn_sched_barrier(0);                                           \
    {                                                                            \
      unsigned v = *(const unsigned*)&Ho[bb][jp];                                \
      sc_store4(hdec + (size_t)(t & 1) * 16384 + (size_t)bb * 512 + nb * 32 + jp, v); \
      sc_store4(decb + ((size_t)bb * cTM1 + t) * 1024 + 512 + nb * 32 + jp, v);  \
    }                                                                            \
    __builtin_amdgcn_sched_barrier(0);                                           \
    const int tn = (t < cTM1 - 1) ? t + 1 : cTM1 - 1;                            \
    ZO0 = *(const f32x4*)(yW + ((size_t)(tn * 32 + b0)) * 2048 + zc);            \
    ZO1 = *(const f32x4*)(yW + ((size_t)(tn * 32 + b1)) * 2048 + zc);            \
    if (t < cTM1 - 1) SLOT_BARRIER(slots, nb, t + 1);                            \
  }

__global__ __launch_bounds__(512, 1) void k_dec_mfma(
    const float* __restrict__ yW, const __hip_bfloat16* __restrict__ Utd,
    const float* __restrict__ prev_h, const float* __restrict__ prev_c,
    __hip_bfloat16* __restrict__ hdec, __hip_bfloat16* __restrict__ decb,
    const float* __restrict__ clsW, __hip_bfloat16* __restrict__ clsWt,
    const float* __restrict__ src_h, const float* __restrict__ neg,
    unsigned* slots) {
  __shared__ __hip_bfloat16 Hs[32][520];
  __shared__ __hip_bfloat16 Ho[32][36];
  __shared__ float tcv[32][33];
  __shared__ float hv_sh[512];
  __shared__ float sc_sh[128];
  __shared__ float red_sh[128];

  const int tid = threadIdx.x;
  const int lane = tid & 63;
  const int wv = tid >> 6;

  if (blockIdx.x >= 16) {
    const int sidx = blockIdx.x - 16;   // 0..239
    // 1) classifier weight transpose-convert (clsWt aliases xWf/xWb: dead now)
    for (int tile = sidx; tile < 32000; tile += 240) {
      f2bT_tile512(clsW, clsWt, 1024, 32000, tile % 1000, tile / 1000, tcv);
    }
    // 2) slot-gated attention tasks (i = t*32 + b, t nondecreasing)
    unsigned waited = 0;
    for (int i = sidx; i < 2016; i += 240) {
      int t = i >> 5, b = i & 31;
      unsigned need = (unsigned)(t + 1);
      if (need > waited) {
        if (wv == 0) {
          for (;;) {
            unsigned v = sc_loadu(slots + (lane & 15));
            if (__all((lane >= 16) | (v >= need))) break;
            __builtin_amdgcn_s_sleep(4);
          }
        }
        __syncthreads();
        waited = need;
      }
      attn_one(src_h, neg, decb, b, t, hv_sh, sc_sh, red_sh);
    }
    return;
  }

  const int nb = blockIdx.x;      // 0..15
  const int c0 = nb * 128;
  const int fr = lane & 15;
  const int fq = lane >> 4;

  bf16x8 afrag[16];
#pragma unroll
  for (int kk = 0; kk < 16; ++kk)
    afrag[kk] = *(const bf16x8*)(Utd + (size_t)(c0 + wv * 16 + fr) * 512 + kk * 32 + fq * 8);

  const int jglob = nb * 32 + wv * 4 + fq;
  const int jloc = wv * 4 + fq;
  const int b0 = fr, b1 = fr + 16;
  const int zc = c0 + wv * 16 + fq * 4;
  const int bb = tid >> 4, jp = (tid & 15) * 2;
  float cs0 = prev_c[(size_t)b0 * 512 + jglob];
  float cs1 = prev_c[(size_t)b1 * 512 + jglob];

  f32x4 zA0 = *(const f32x4*)(yW + ((size_t)b0) * 2048 + zc);
  f32x4 zA1 = *(const f32x4*)(yW + ((size_t)b1) * 2048 + zc);
  f32x4 zB0, zB1;

  for (int it = 0; it < 31; ++it) {
    DEC_STEP(2 * it, zA0, zA1, zB0, zB1);
    DEC_STEP(2 * it + 1, zB0, zB1, zA0, zA1);
  }
  DEC_STEP(62, zA0, zA1, zB0, zB1);
  // publish final generation so attention for t=62 can proceed
  asm volatile("s_waitcnt vmcnt(0)" ::: "memory");
  __builtin_amdgcn_s_barrier();
  if (tid == 0) sc_storeu(slots + nb, (unsigned)cTM1);
}

extern "C" void kernel_launch(void* const* d_in, const int* in_sizes, int n_in,
                              void* d_out, int out_size, void* d_ws, size_t ws_size,
                              hipStream_t stream) {
  const int* src = (const int*)d_in[0];
  const int* trg = (const int*)d_in[1];
  const float* E_src = (const float*)d_in[2];
  const float* E_trg = (const float*)d_in[3];
  const float* Wf = (const float*)d_in[4];
  const float* Uf = (const float*)d_in[5];
  const float* bf = (const float*)d_in[6];
  const float* Wb = (const float*)d_in[7];
  const float* Ub = (const float*)d_in[8];
  const float* bb = (const float*)d_in[9];
  const float* Wd = (const float*)d_in[10];
  const float* Ud = (const float*)d_in[11];
  const float* bd = (const float*)d_in[12];
  const float* fcW = (const float*)d_in[13];
  const float* fcb = (const float*)d_in[14];
  const float* clsW = (const float*)d_in[15];
  const float* clsb = (const float*)d_in[16];
  float* out = (float*)d_out;
  float* ws = (float*)d_ws;

  // ---- static layout (float offsets) ----
  float* xWf = ws;                                           // 8388608
  float* xWb = ws + 8388608;                                 // -> 16777216
  float* yW = ws + 16777216;                                 // 2048x2048 -> 20971520 (+gap)
  float* neg = ws + 23035904;                                // -> 23040000
  float* fco = ws + 23040000;                                // 2129920 -> 25169920
  __hip_bfloat16* decb = (__hip_bfloat16*)(ws + 25169920);   // 2048x1024 bf16, b-major rows
  __hip_bfloat16* Utd = (__hip_bfloat16*)(ws + 26218496);    // -> 26742784
  __hip_bfloat16* henc = (__hip_bfloat16*)(ws + 26742784);   // -> 26808320
  __hip_bfloat16* hdec = (__hip_bfloat16*)(ws + 26808320);   // -> 26841088
  unsigned* bars = (unsigned*)(ws + 26841088);               // 64 uints -> 26841152
  float* pool = ws + 26841152;

  // pool transients (pre-encoder)
  __hip_bfloat16* xs_bf = (__hip_bfloat16*)pool;              // 1048576 fl
  __hip_bfloat16* ys_bf = (__hip_bfloat16*)(pool + 1048576);  // 524288 fl
  __hip_bfloat16* Utf = (__hip_bfloat16*)(pool + 1572864);    // 524288 fl
  __hip_bfloat16* Utb = (__hip_bfloat16*)(pool + 2097152);    // 524288 fl -> 2621440
  __hip_bfloat16* Wtfx = (__hip_bfloat16*)(pool + 2621440);   // 524288 fl
  __hip_bfloat16* Wtbx = (__hip_bfloat16*)(pool + 3145728);   // 524288 fl
  __hip_bfloat16* Wtdx = (__hip_bfloat16*)(pool + 3670016);   // 524288 fl
  float* bfx = pool + 4194304;                                // 2048
  float* bbx = pool + 4196352;                                // 2048
  float* bdx = pool + 4198400;                                // 2048 -> 4200448
  __hip_bfloat16* fcWt = (__hip_bfloat16*)(pool + 4200448);   // 262144 fl -> 4462592
  __hip_bfloat16* cat_bf = (__hip_bfloat16*)(pool + 4462592); // 4224x1024 bf16 -> 6625280
  __hip_bfloat16* clsWt = (__hip_bfloat16*)xWf;               // 32000x1024 bf16 (xWf/xWb dead post-encoder)

  // phase A: mega-prep (weights + biases + embeds + pads + barrier init)
  k_prep<<<9833, 256, 0, stream>>>(Wf, Wb, Wd, Uf, Ub, Ud, fcW, bf, bb, bd,
                                   src, trg, E_src, E_trg,
                                   Wtfx, Wtbx, Wtdx, Utf, Utb, Utd, fcWt,
                                   bfx, bbx, bdx, xs_bf, ys_bf, neg, cat_bf, bars);

  // encoder input projections (one launch, z = {fwd,bwd})
  k_bgemm2<<<dim3(32, 16, 2), 256, 0, stream>>>(xs_bf, Wtfx, Wtbx, bfx, bbx,
                                                xWf, xWb, 4096, 512, 2048);

  // phase B: persistent MFMA encoder (+ yW projection in side blocks)
  k_enc_mfma<<<256, 512, 0, stream>>>(xWf, xWb, Utf, Utb, cat_bf, henc, bars,
                                      ys_bf, Wtdx, bdx, yW);

  // phase C: fc projection (cat rows fully written by encoder)
  k_bgemm<<<dim3(33, 4), 256, 0, stream>>>(cat_bf, fcWt, fcb, fco, 4160, 1024, 512);

  // phase D: persistent MFMA decoder; side blocks convert clsW then run attention
  const float* prev_h = fco + (size_t)4096 * 512;
  const float* prev_c = fco + (size_t)4128 * 512;
  k_dec_mfma<<<256, 512, 0, stream>>>(yW, Utd, prev_h, prev_c, hdec, decb,
                                      clsW, clsWt, fco, neg, bars + 32);

  // phase F: classifier
  k_bgemm<<<dim3(16, 250), 256, 0, stream>>>(decb, clsWt, clsb, out, 2016, 1024, 32000);
}